// Round 5
// baseline (667.639 us; speedup 1.0000x reference)
//
#include <hip/hip_runtime.h>
#include <cstdint>

typedef _Float16 f16;
typedef __attribute__((ext_vector_type(8))) _Float16 f16x8;
typedef __attribute__((ext_vector_type(4))) _Float16 f16x4;
typedef __attribute__((ext_vector_type(2))) _Float16 f16x2;
typedef __attribute__((ext_vector_type(4))) float f32x4;
typedef __attribute__((ext_vector_type(16))) float f32x16;

#define D_MODEL 1024
#define T_SEQ   2048
#define NTOK    8192      // B*T
#define DFF     4096
#define DHEAD   64

struct alignas(16) H8 { f16 h[8]; };

// async global->LDS, 16B per lane. LDS dest must be wave-uniform base; HW adds lane*16.
__device__ __forceinline__ void load_lds16(const void* gp, void* lp) {
  __builtin_amdgcn_global_load_lds(
      (const __attribute__((address_space(1))) unsigned int*)(unsigned long long)(uintptr_t)gp,
      (__attribute__((address_space(3))) unsigned int*)(unsigned int)(uintptr_t)lp,
      16, 0, 0);
}

// out[c][r] = (f16) in[r][c];  in: [rows][cols] fp32 row-major. All dims %32==0.
__global__ __launch_bounds__(256) void transpose_pack(
    const float* __restrict__ in, f16* __restrict__ out,
    int rows, int cols, long long in_slice, long long out_slice)
{
  __shared__ float tile[32][33];
  const float* inp = in + (size_t)blockIdx.z * in_slice;
  f16* outp = out + (size_t)blockIdx.z * out_slice;
  int r0 = blockIdx.x * 32, c0 = blockIdx.y * 32;
  int tx = threadIdx.x & 31, ty = threadIdx.x >> 5;   // 32 x 8
  #pragma unroll
  for (int i = 0; i < 4; ++i)
    tile[ty + i*8][tx] = inp[(size_t)(r0 + ty + i*8)*cols + c0 + tx];
  __syncthreads();
  #pragma unroll
  for (int i = 0; i < 4; ++i)
    outp[(size_t)(c0 + ty + i*8)*rows + r0 + tx] = (f16)tile[tx][ty + i*8];
}

// row-wise layernorm over 1024; writes fp32 (residual path) + f16 (GEMM input)
__global__ __launch_bounds__(256) void ln_kernel(
    const float* __restrict__ x, const float* __restrict__ g, const float* __restrict__ b,
    float* __restrict__ outf, f16* __restrict__ outh)
{
  int row = blockIdx.x;
  const float* xr = x + (size_t)row * D_MODEL;
  int tid = threadIdx.x;
  float v[4];
  float s = 0.f;
  #pragma unroll
  for (int i = 0; i < 4; ++i) { v[i] = xr[tid + i*256]; s += v[i]; }
  #pragma unroll
  for (int off = 32; off > 0; off >>= 1) s += __shfl_down(s, off, 64);
  __shared__ float red1[4], red2[4];
  if ((tid & 63) == 0) red1[tid >> 6] = s;
  __syncthreads();
  float mean = (red1[0] + red1[1] + red1[2] + red1[3]) * (1.f / D_MODEL);
  float s2 = 0.f;
  #pragma unroll
  for (int i = 0; i < 4; ++i) { float d = v[i] - mean; s2 += d * d; }
  #pragma unroll
  for (int off = 32; off > 0; off >>= 1) s2 += __shfl_down(s2, off, 64);
  if ((tid & 63) == 0) red2[tid >> 6] = s2;
  __syncthreads();
  float var = (red2[0] + red2[1] + red2[2] + red2[3]) * (1.f / D_MODEL);
  float rstd = rsqrtf(var + 1e-5f);
  #pragma unroll
  for (int i = 0; i < 4; ++i) {
    int c = tid + i*256;
    float y = (v[i] - mean) * rstd * g[c] + b[c];
    outf[(size_t)row*D_MODEL + c] = y;
    outh[(size_t)row*D_MODEL + c] = (f16)y;
  }
}

// GEMM: C[M,N] = A[M,K] * BT[N,K]^T, f16 in, fp32 acc, 32x32x16 MFMA.
// 256x128 block, BK=32; 4 waves in 2x2, each wave 128x64 (4x2 tiles).
// LDS k-chunks XOR-swizzled: LDS[row][pos] = global chunk (pos ^ ((row>>2)&3));
// frag reads apply matching XOR -> even bank coverage (structural 8 cyc/b128)
// under the global_load_lds lane-contiguous constraint.
// MODE 0: scatter q/k/v (q scaled log2e/32) -> o0,o1,o2 [BH][T][64] f16
// MODE 1: outf = acc + bias[col] + resid[idx]            (proj, fp32)
// MODE 2: o0   = relu(acc + bias[col])                   (ffn1, f16, ld 4096)
// MODE 3: outf = acc + bias[col] + resid[idx]            (ffn2 -> d_out)
template<int MODE>
__global__ __launch_bounds__(256) void gemm_kernel(
    const f16* __restrict__ A, const f16* __restrict__ BT, int K,
    const float* __restrict__ bias, const float* __restrict__ resid,
    float* __restrict__ outf, f16* __restrict__ o0, f16* __restrict__ o1, f16* __restrict__ o2)
{
  constexpr int BM = 256, BN = 128, BK = 32;
  __shared__ __align__(16) f16 As[BM * BK];   // 16 KB
  __shared__ __align__(16) f16 Bs[BN * BK];   // 8 KB
  int tid  = threadIdx.x;
  int lane = tid & 63;
  int wave = tid >> 6;
  int wm = (wave >> 1) * 128, wn = (wave & 1) * 64;
  size_t row0 = (size_t)blockIdx.x * BM, col0 = (size_t)blockIdx.y * BN;
  int rl = lane & 31;             // row/col within 32-tile
  int half = lane >> 5;           // k-half of the wave
  int swz = (rl >> 2) & 3;        // read-side chunk swizzle for this lane's rows

  f32x16 acc[4][2];
  #pragma unroll
  for (int i = 0; i < 4; ++i)
    #pragma unroll
    for (int j = 0; j < 2; ++j)
      acc[i][j] = (f32x16)(0.f);

  const f16* a_base = A  + row0 * K;
  const f16* b_base = BT + col0 * K;

  for (int k0 = 0; k0 < K; k0 += BK) {
    __syncthreads();
    // stage A: 1024 chunks (row=c>>2, pos=c&3 holds global chunk pos^((row>>2)&3))
    #pragma unroll
    for (int i = 0; i < 4; ++i) {
      int c  = tid + i * 256;
      int rr = c >> 2;
      int cg = (c & 3) ^ ((c >> 4) & 3);
      load_lds16(a_base + (size_t)rr * K + k0 + cg * 8, As + (size_t)(c & ~63) * 8);
    }
    // stage B: 512 chunks
    #pragma unroll
    for (int i = 0; i < 2; ++i) {
      int c  = tid + i * 256;
      int rr = c >> 2;
      int cg = (c & 3) ^ ((c >> 4) & 3);
      load_lds16(b_base + (size_t)rr * K + k0 + cg * 8, Bs + (size_t)(c & ~63) * 8);
    }
    __syncthreads();   // drains vmcnt for global_load_lds
    // frags (32x32x16): lane holds [m=rl][k = half*8 + j]; logical chunk ks*2+half
    #pragma unroll
    for (int ks = 0; ks < 2; ++ks) {
      int chunk = (ks * 2 + half) ^ swz;
      f16x8 fa[4], fb[2];
      #pragma unroll
      for (int mi = 0; mi < 4; ++mi)
        fa[mi] = *(const f16x8*)(As + (wm + mi*32 + rl) * BK + chunk * 8);
      #pragma unroll
      for (int ni = 0; ni < 2; ++ni)
        fb[ni] = *(const f16x8*)(Bs + (wn + ni*32 + rl) * BK + chunk * 8);
      #pragma unroll
      for (int mi = 0; mi < 4; ++mi)
        #pragma unroll
        for (int ni = 0; ni < 2; ++ni)
          acc[mi][ni] = __builtin_amdgcn_mfma_f32_32x32x16_f16(fa[mi], fb[ni], acc[mi][ni], 0, 0, 0);
    }
  }

  // epilogue: 32x32 C layout (m74/m101): col=lane&31, row=(reg&3)+8*(reg>>2)+4*(lane>>5)
  int rbase = half * 4;
  #pragma unroll
  for (int mi = 0; mi < 4; ++mi) {
    #pragma unroll
    for (int ni = 0; ni < 2; ++ni) {
      #pragma unroll
      for (int r = 0; r < 16; ++r) {
        size_t grow = row0 + wm + mi*32 + rbase + (r & 3) + 8 * (r >> 2);
        size_t gcol = col0 + wn + ni*32 + rl;
        float v = acc[mi][ni][r];
        if constexpr (MODE == 0) {
          int sel = (int)(gcol >> 10);
          int hh  = ((int)gcol >> 6) & 15;
          int dd  = (int)gcol & 63;
          f16* dst = (sel == 0) ? o0 : ((sel == 1) ? o1 : o2);
          if (sel == 0) v *= 0.045084229f;   // (1/32) * log2(e): exp2-domain scores
          size_t bh = (grow >> 11) * 16 + hh;
          dst[(bh * T_SEQ + (grow & 2047)) * DHEAD + dd] = (f16)v;
        } else if constexpr (MODE == 1 || MODE == 3) {
          size_t idx = grow * D_MODEL + gcol;
          outf[idx] = v + bias[gcol] + resid[idx];
        } else {  // MODE 2
          float t = v + bias[gcol];
          o0[grow * (size_t)DFF + gcol] = (f16)(t > 0.f ? t : 0.f);
        }
      }
    }
  }
}

// MFMA flash attention, S^T formulation + fixed-max softmax.
// Block = 4 waves x 32 q-rows = 128 q-rows; two q-tiles per block (qi=15-bx, bx)
// for uniform 34 k-tiles/block. Scores arrive already in log2 domain (q scaled
// by log2e/32 at QKV epilogue), softmax max fixed at 0 (scores have std ~0.36
// in log2 domain -- exp2 cannot overflow; softmax is shift-invariant so exact).
// S^T = K*Q^T puts each q-row's keys in ONE lane's registers: no per-tile
// shuffles; P^T lane data is key-contiguous -> b64 LDS writes, b128 A-frag reads.
__global__ __launch_bounds__(256) void attn_mfma(
    const f16* __restrict__ qb, const f16* __restrict__ kb,
    const f16* __restrict__ vb, f16* __restrict__ attnb)
{
  constexpr int KT  = 64;
  constexpr int LDK = 72;                        // padded f16 stride (K, Vt, Pt)
  __shared__ __align__(16) f16 Kl[KT * LDK];     // [key][d]
  __shared__ __align__(16) f16 Vt[DHEAD * LDK];  // [d][key]
  __shared__ __align__(16) f16 Pt[4 * 32 * LDK]; // per-wave [q 0..31][key]

  int tid  = threadIdx.x;
  int lane = tid & 63, wave = tid >> 6;
  int n    = lane & 15, quad = lane >> 4;
  int quad4 = quad * 4;
  int bh   = blockIdx.y;

  const f16* qg = qb + (size_t)bh * T_SEQ * DHEAD;
  const f16* kg = kb + (size_t)bh * T_SEQ * DHEAD;
  const f16* vg = vb + (size_t)bh * T_SEQ * DHEAD;
  f16* Ptw = Pt + wave * 32 * LDK;
  size_t orow = (size_t)(bh >> 4) * T_SEQ;
  int hcol = (bh & 15) * DHEAD;

  #pragma unroll
  for (int pass = 0; pass < 2; ++pass) {
    int qi = pass == 0 ? (15 - (int)blockIdx.x) : (int)blockIdx.x;  // heavy first
    int qw = qi * 128 + wave * 32;               // this wave's first q row

    // Q fragments (B-operand): lane n holds Q[q=qw+ni*16+n][d=quad*8+j]
    f16x8 qfrag[2][2];
    #pragma unroll
    for (int ni = 0; ni < 2; ++ni)
      #pragma unroll
      for (int kj = 0; kj < 2; ++kj)
        qfrag[ni][kj] = *(const f16x8*)(qg + (size_t)(qw + ni*16 + n)*DHEAD + kj*32 + quad*8);

    f32x4 o[2][4];
    #pragma unroll
    for (int mb = 0; mb < 2; ++mb)
      #pragma unroll
      for (int di = 0; di < 4; ++di) o[mb][di] = f32x4{0.f,0.f,0.f,0.f};
    float lsum[2] = {0.f, 0.f};

    int ntiles = 2 * qi + 2;
    for (int kt = 0; kt < ntiles; ++kt) {
      int kt0 = kt * KT;
      __syncthreads();                           // prev tile fully consumed
      // stage K [64 keys][64 d], coalesced 16B
      #pragma unroll
      for (int it = 0; it < 2; ++it) {
        int idx = tid + it * 256;
        int key = idx >> 3, dq = idx & 7;
        *(uint4*)(Kl + key * LDK + dq * 8) =
            *(const uint4*)(kg + (size_t)(kt0 + key) * DHEAD + dq * 8);
      }
      // stage V transposed, packed f16x2 writes (adjacent keys share a dword)
      {
        int kp = tid & 31, dblk = tid >> 5;      // keys 2kp,2kp+1; d = dblk*8+e
        const f16* v0 = vg + (size_t)(kt0 + 2*kp) * DHEAD + dblk * 8;
        H8 va = *(const H8*)v0;
        H8 vbv = *(const H8*)(v0 + DHEAD);
        #pragma unroll
        for (int e = 0; e < 8; ++e) {
          f16x2 pk2; pk2[0] = va.h[e]; pk2[1] = vbv.h[e];
          *(f16x2*)(Vt + (dblk*8 + e) * LDK + 2*kp) = pk2;
        }
      }
      __syncthreads();

      if (kt0 > qw + 31) continue;               // fully masked for this wave
      bool need_mask = (kt0 + KT - 1) > qw;      // diagonal tile

      // S^T = K Q^T : [64 key][32 q]; lane holds (key=mi*16+quad4+r, q=ni*16+n)
      f32x4 st[4][2];
      #pragma unroll
      for (int mi = 0; mi < 4; ++mi)
        #pragma unroll
        for (int ni = 0; ni < 2; ++ni) st[mi][ni] = f32x4{0.f,0.f,0.f,0.f};
      #pragma unroll
      for (int kj = 0; kj < 2; ++kj) {
        #pragma unroll
        for (int mi = 0; mi < 4; ++mi) {
          f16x8 kf = *(const f16x8*)(Kl + (mi*16 + n) * LDK + kj*32 + quad*8);
          #pragma unroll
          for (int ni = 0; ni < 2; ++ni)
            st[mi][ni] = __builtin_amdgcn_mfma_f32_16x16x32_f16(kf, qfrag[ni][kj], st[mi][ni], 0, 0, 0);
        }
      }

      // p = exp2(s'); per-lane row-sum accumulate; P^T -> LDS (b64, key-contig)
      #pragma unroll
      for (int ni = 0; ni < 2; ++ni) {
        #pragma unroll
        for (int mi = 0; mi < 4; ++mi) {
          f16x4 pk;
          #pragma unroll
          for (int r = 0; r < 4; ++r) {
            float sv = st[mi][ni][r];
            if (need_mask) {
              int key = kt0 + mi*16 + quad4 + r;
              int qq  = qw  + ni*16 + n;
              if (key > qq) sv = -1e30f;
            }
            float p = __builtin_amdgcn_exp2f(sv);
            lsum[ni] += p;
            pk[r] = (f16)p;
          }
          *(f16x4*)(Ptw + (ni*16 + n) * LDK + mi*16 + quad4) = pk;
        }
      }

      // O += P V : A-frag = Pt rows (b128, same-wave RAW), B-frag = Vt rows
      #pragma unroll
      for (int kj = 0; kj < 2; ++kj) {
        f16x8 pf[2];
        #pragma unroll
        for (int mb = 0; mb < 2; ++mb)
          pf[mb] = *(const f16x8*)(Ptw + (mb*16 + n) * LDK + kj*32 + quad*8);
        #pragma unroll
        for (int di = 0; di < 4; ++di) {
          f16x8 vf = *(const f16x8*)(Vt + (di*16 + n) * LDK + kj*32 + quad*8);
          #pragma unroll
          for (int mb = 0; mb < 2; ++mb)
            o[mb][di] = __builtin_amdgcn_mfma_f32_16x16x32_f16(pf[mb], vf, o[mb][di], 0, 0, 0);
        }
      }
    }

    // finish l: quads hold disjoint key-subsets of each q-row -> 2 shuffles
    #pragma unroll
    for (int ni = 0; ni < 2; ++ni) {
      lsum[ni] += __shfl_xor(lsum[ni], 16, 64);
      lsum[ni] += __shfl_xor(lsum[ni], 32, 64);
    }
    // epilogue: O C-layout lane holds (q=mb*16+quad4+r, d=di*16+n)
    #pragma unroll
    for (int mb = 0; mb < 2; ++mb) {
      #pragma unroll
      for (int r = 0; r < 4; ++r) {
        float lv  = __shfl(lsum[mb], quad4 + r, 64);   // lane n'=quad4+r holds q's sum
        float inv = 1.f / lv;
        int t = qw + mb*16 + quad4 + r;
        #pragma unroll
        for (int di = 0; di < 4; ++di)
          attnb[(orow + t) * D_MODEL + hcol + di*16 + n] = (f16)(o[mb][di][r] * inv);
      }
    }
  }
}

extern "C" void kernel_launch(void* const* d_in, const int* in_sizes, int n_in,
                              void* d_out, int out_size, void* d_ws, size_t ws_size,
                              hipStream_t stream)
{
  const float* x     = (const float*)d_in[0];
  const float* Wq    = (const float*)d_in[1];
  const float* Wk    = (const float*)d_in[2];
  const float* Wv    = (const float*)d_in[3];
  const float* Wproj = (const float*)d_in[4];
  const float* bproj = (const float*)d_in[5];
  const float* W1    = (const float*)d_in[6];
  const float* b1    = (const float*)d_in[7];
  const float* W2    = (const float*)d_in[8];
  const float* b2    = (const float*)d_in[9];
  const float* g1    = (const float*)d_in[10];
  const float* bt1   = (const float*)d_in[11];
  const float* g2    = (const float*)d_in[12];
  const float* bt2   = (const float*)d_in[13];
  float* out = (float*)d_out;
  (void)in_sizes; (void)n_in; (void)out_size; (void)ws_size;

  char* ws = (char*)d_ws;
  const size_t SZ_H16 = (size_t)NTOK * D_MODEL * 2;  // 16.78 MB
  const size_t SZ_F32 = (size_t)NTOK * D_MODEL * 4;  // 33.55 MB
  f16*   qb      = (f16*)(ws + 0);
  f16*   kb      = (f16*)(ws + 1 * SZ_H16);
  f16*   vb      = (f16*)(ws + 2 * SZ_H16);
  f16*   attnb   = (f16*)(ws + 3 * SZ_H16);
  f16*   hbuf    = (f16*)(ws + 0);                   // reuses q/k/v/attn after proj (67.1MB)
  float* x1f     = (float*)(ws + 4 * SZ_H16);        // becomes x2 in-place at proj
  f16*   x1h     = (f16*)(ws + 4 * SZ_H16 + SZ_F32);
  float* x3f     = (float*)(ws + 5 * SZ_H16 + SZ_F32);
  f16*   x3h     = (f16*)(ws + 5 * SZ_H16 + 2 * SZ_F32);
  char*  wb      = ws + 6 * SZ_H16 + 2 * SZ_F32;
  f16*   Wqkv_t  = (f16*)(wb);                                       // [3072][1024]
  f16*   Wproj_t = (f16*)(wb + (size_t)3072*1024*2);                 // [1024][1024]
  f16*   W1_t    = (f16*)(wb + (size_t)(3072+1024)*1024*2);          // [4096][1024]
  f16*   W2_t    = (f16*)(wb + (size_t)(3072+1024+4096)*1024*2);     // [1024][4096]

  dim3 blk(256);
  // ---- pack weights to f16 B^T layouts
  transpose_pack<<<dim3(32, 2, 16), blk, 0, stream>>>(Wq, Wqkv_t,                 1024, 64,  65536, 65536);
  transpose_pack<<<dim3(32, 2, 16), blk, 0, stream>>>(Wk, Wqkv_t + 1024*1024,     1024, 64,  65536, 65536);
  transpose_pack<<<dim3(32, 2, 16), blk, 0, stream>>>(Wv, Wqkv_t + 2*1024*1024,   1024, 64,  65536, 65536);
  transpose_pack<<<dim3(32, 32, 1), blk, 0, stream>>>(Wproj, Wproj_t, 1024, 1024, 0, 0);
  transpose_pack<<<dim3(32, 128, 1), blk, 0, stream>>>(W1, W1_t, 1024, 4096, 0, 0);
  transpose_pack<<<dim3(128, 32, 1), blk, 0, stream>>>(W2, W2_t, 4096, 1024, 0, 0);
  // ---- ln1
  ln_kernel<<<NTOK, blk, 0, stream>>>(x, g1, bt1, x1f, x1h);
  // ---- fused QKV gemm [8192,1024] x [1024,3072]
  gemm_kernel<0><<<dim3(32, 24), blk, 0, stream>>>(x1h, Wqkv_t, 1024, nullptr, nullptr, nullptr, qb, kb, vb);
  // ---- attention (MFMA flash, S^T + fixed-max)
  attn_mfma<<<dim3(8, 64), blk, 0, stream>>>(qb, kb, vb, attnb);
  // ---- proj + bias + residual(x1) -> x2 (in place over x1f)
  gemm_kernel<1><<<dim3(32, 8), blk, 0, stream>>>(attnb, Wproj_t, 1024, bproj, x1f, x1f, nullptr, nullptr, nullptr);
  // ---- ln2
  ln_kernel<<<NTOK, blk, 0, stream>>>(x1f, g2, bt2, x3f, x3h);
  // ---- ffn1: relu(x3 @ W1 + b1)
  gemm_kernel<2><<<dim3(32, 32), blk, 0, stream>>>(x3h, W1_t, 1024, b1, nullptr, nullptr, hbuf, nullptr, nullptr);
  // ---- ffn2: x3 + h @ W2 + b2 -> out
  gemm_kernel<3><<<dim3(32, 8), blk, 0, stream>>>(hbuf, W2_t, 4096, b2, x3f, out, nullptr, nullptr, nullptr);
}

// Round 6
// 536.611 us; speedup vs baseline: 1.2442x; 1.2442x over previous
//
#include <hip/hip_runtime.h>
#include <cstdint>

typedef _Float16 f16;
typedef __attribute__((ext_vector_type(8))) _Float16 f16x8;
typedef __attribute__((ext_vector_type(4))) _Float16 f16x4;
typedef __attribute__((ext_vector_type(2))) _Float16 f16x2;
typedef __attribute__((ext_vector_type(4))) float f32x4;
typedef __attribute__((ext_vector_type(16))) float f32x16;

#define D_MODEL 1024
#define T_SEQ   2048
#define NTOK    8192      // B*T
#define DFF     4096
#define DHEAD   64

struct alignas(16) H8 { f16 h[8]; };

// async global->LDS, 16B per lane. LDS dest must be wave-uniform base; HW adds lane*16.
__device__ __forceinline__ void load_lds16(const void* gp, void* lp) {
  __builtin_amdgcn_global_load_lds(
      (const __attribute__((address_space(1))) unsigned int*)(unsigned long long)(uintptr_t)gp,
      (__attribute__((address_space(3))) unsigned int*)(unsigned int)(uintptr_t)lp,
      16, 0, 0);
}

// out[c][r] = (f16) in[r][c];  in: [rows][cols] fp32 row-major. All dims %32==0.
__global__ __launch_bounds__(256) void transpose_pack(
    const float* __restrict__ in, f16* __restrict__ out,
    int rows, int cols, long long in_slice, long long out_slice)
{
  __shared__ float tile[32][33];
  const float* inp = in + (size_t)blockIdx.z * in_slice;
  f16* outp = out + (size_t)blockIdx.z * out_slice;
  int r0 = blockIdx.x * 32, c0 = blockIdx.y * 32;
  int tx = threadIdx.x & 31, ty = threadIdx.x >> 5;   // 32 x 8
  #pragma unroll
  for (int i = 0; i < 4; ++i)
    tile[ty + i*8][tx] = inp[(size_t)(r0 + ty + i*8)*cols + c0 + tx];
  __syncthreads();
  #pragma unroll
  for (int i = 0; i < 4; ++i)
    outp[(size_t)(c0 + ty + i*8)*rows + r0 + tx] = (f16)tile[tx][ty + i*8];
}

// row-wise layernorm over 1024; writes fp32 (residual path) + f16 (GEMM input)
__global__ __launch_bounds__(256) void ln_kernel(
    const float* __restrict__ x, const float* __restrict__ g, const float* __restrict__ b,
    float* __restrict__ outf, f16* __restrict__ outh)
{
  int row = blockIdx.x;
  const float* xr = x + (size_t)row * D_MODEL;
  int tid = threadIdx.x;
  float v[4];
  float s = 0.f;
  #pragma unroll
  for (int i = 0; i < 4; ++i) { v[i] = xr[tid + i*256]; s += v[i]; }
  #pragma unroll
  for (int off = 32; off > 0; off >>= 1) s += __shfl_down(s, off, 64);
  __shared__ float red1[4], red2[4];
  if ((tid & 63) == 0) red1[tid >> 6] = s;
  __syncthreads();
  float mean = (red1[0] + red1[1] + red1[2] + red1[3]) * (1.f / D_MODEL);
  float s2 = 0.f;
  #pragma unroll
  for (int i = 0; i < 4; ++i) { float d = v[i] - mean; s2 += d * d; }
  #pragma unroll
  for (int off = 32; off > 0; off >>= 1) s2 += __shfl_down(s2, off, 64);
  if ((tid & 63) == 0) red2[tid >> 6] = s2;
  __syncthreads();
  float var = (red2[0] + red2[1] + red2[2] + red2[3]) * (1.f / D_MODEL);
  float rstd = rsqrtf(var + 1e-5f);
  #pragma unroll
  for (int i = 0; i < 4; ++i) {
    int c = tid + i*256;
    float y = (v[i] - mean) * rstd * g[c] + b[c];
    outf[(size_t)row*D_MODEL + c] = y;
    outh[(size_t)row*D_MODEL + c] = (f16)y;
  }
}

// GEMM: C[M,N] = A[M,K] * BT[N,K]^T, f16 in, fp32 acc, 32x32x16 MFMA.
// 128x128 block (m103 sweet spot: grids 512-2048 blocks = 2-8/CU oversub),
// BK=32; 4 waves in 2x2, each wave 64x64 (2x2 tiles).
// LDS k-chunks XOR-swizzled (R5-verified: SQ_LDS_BANK_CONFLICT=0):
// LDS[row][pos] holds global chunk (pos ^ ((row>>2)&3)); frag reads XOR back.
// MODE 0: scatter q/k/v (q scaled log2e/32) -> o0,o1,o2 [BH][T][64] f16
// MODE 1: outf = acc + bias[col] + resid[idx]            (proj, fp32)
// MODE 2: o0   = relu(acc + bias[col])                   (ffn1, f16, ld 4096)
// MODE 3: outf = acc + bias[col] + resid[idx]            (ffn2 -> d_out)
template<int MODE>
__global__ __launch_bounds__(256) void gemm_kernel(
    const f16* __restrict__ A, const f16* __restrict__ BT, int K,
    const float* __restrict__ bias, const float* __restrict__ resid,
    float* __restrict__ outf, f16* __restrict__ o0, f16* __restrict__ o1, f16* __restrict__ o2)
{
  constexpr int BM = 128, BN = 128, BK = 32;
  __shared__ __align__(16) f16 As[BM * BK];   // 8 KB
  __shared__ __align__(16) f16 Bs[BN * BK];   // 8 KB
  int tid  = threadIdx.x;
  int lane = tid & 63;
  int wave = tid >> 6;
  int wm = (wave >> 1) * 64, wn = (wave & 1) * 64;
  size_t row0 = (size_t)blockIdx.x * BM, col0 = (size_t)blockIdx.y * BN;
  int rl = lane & 31;             // row/col within 32-tile
  int half = lane >> 5;           // k-half of the wave
  int swz = (rl >> 2) & 3;        // read-side chunk swizzle for this lane's rows

  f32x16 acc[2][2];
  #pragma unroll
  for (int i = 0; i < 2; ++i)
    #pragma unroll
    for (int j = 0; j < 2; ++j)
      acc[i][j] = (f32x16)(0.f);

  const f16* a_base = A  + row0 * K;
  const f16* b_base = BT + col0 * K;

  for (int k0 = 0; k0 < K; k0 += BK) {
    __syncthreads();
    // stage A+B: 512 chunks each; slot (row=c>>2, pos=c&3) holds global
    // k-chunk (pos ^ ((row>>2)&3))  [swizzle is in the SOURCE address only]
    #pragma unroll
    for (int i = 0; i < 2; ++i) {
      int c  = tid + i * 256;
      int rr = c >> 2;
      int cg = (c & 3) ^ ((c >> 4) & 3);
      load_lds16(a_base + (size_t)rr * K + k0 + cg * 8, As + (size_t)(c & ~63) * 8);
      load_lds16(b_base + (size_t)rr * K + k0 + cg * 8, Bs + (size_t)(c & ~63) * 8);
    }
    __syncthreads();   // drains vmcnt for global_load_lds
    // frags (32x32x16): lane holds [m=rl][k = half*8 + j]; logical chunk ks*2+half
    #pragma unroll
    for (int ks = 0; ks < 2; ++ks) {
      int chunk = (ks * 2 + half) ^ swz;
      f16x8 fa[2], fb[2];
      #pragma unroll
      for (int mi = 0; mi < 2; ++mi)
        fa[mi] = *(const f16x8*)(As + (wm + mi*32 + rl) * BK + chunk * 8);
      #pragma unroll
      for (int ni = 0; ni < 2; ++ni)
        fb[ni] = *(const f16x8*)(Bs + (wn + ni*32 + rl) * BK + chunk * 8);
      #pragma unroll
      for (int mi = 0; mi < 2; ++mi)
        #pragma unroll
        for (int ni = 0; ni < 2; ++ni)
          acc[mi][ni] = __builtin_amdgcn_mfma_f32_32x32x16_f16(fa[mi], fb[ni], acc[mi][ni], 0, 0, 0);
    }
  }

  // epilogue: 32x32 C layout (m74/m101): col=lane&31, row=(reg&3)+8*(reg>>2)+4*(lane>>5)
  int rbase = half * 4;
  #pragma unroll
  for (int mi = 0; mi < 2; ++mi) {
    #pragma unroll
    for (int ni = 0; ni < 2; ++ni) {
      #pragma unroll
      for (int r = 0; r < 16; ++r) {
        size_t grow = row0 + wm + mi*32 + rbase + (r & 3) + 8 * (r >> 2);
        size_t gcol = col0 + wn + ni*32 + rl;
        float v = acc[mi][ni][r];
        if constexpr (MODE == 0) {
          int sel = (int)(gcol >> 10);
          int hh  = ((int)gcol >> 6) & 15;
          int dd  = (int)gcol & 63;
          f16* dst = (sel == 0) ? o0 : ((sel == 1) ? o1 : o2);
          if (sel == 0) v *= 0.045084229f;   // (1/32) * log2(e): exp2-domain scores
          size_t bh = (grow >> 11) * 16 + hh;
          dst[(bh * T_SEQ + (grow & 2047)) * DHEAD + dd] = (f16)v;
        } else if constexpr (MODE == 1 || MODE == 3) {
          size_t idx = grow * D_MODEL + gcol;
          outf[idx] = v + bias[gcol] + resid[idx];
        } else {  // MODE 2
          float t = v + bias[gcol];
          o0[grow * (size_t)DFF + gcol] = (f16)(t > 0.f ? t : 0.f);
        }
      }
    }
  }
}

// MFMA flash attention, S^T formulation + fixed-max softmax.
// Block = 4 waves x 32 q-rows = 128 q-rows; two q-tiles per block (qi=15-bx, bx)
// for uniform 34 k-tiles/block. Scores arrive already in log2 domain (q scaled
// by log2e/32 at QKV epilogue), softmax max fixed at 0 (scores have std ~0.36
// in log2 domain -- exp2 cannot overflow; softmax is shift-invariant so exact).
// S^T = K*Q^T puts each q-row's keys in ONE lane's registers: no per-tile
// shuffles; P^T lane data is key-contiguous -> b64 LDS writes, b128 A-frag reads.
__global__ __launch_bounds__(256) void attn_mfma(
    const f16* __restrict__ qb, const f16* __restrict__ kb,
    const f16* __restrict__ vb, f16* __restrict__ attnb)
{
  constexpr int KT  = 64;
  constexpr int LDK = 72;                        // padded f16 stride (K, Vt, Pt)
  __shared__ __align__(16) f16 Kl[KT * LDK];     // [key][d]
  __shared__ __align__(16) f16 Vt[DHEAD * LDK];  // [d][key]
  __shared__ __align__(16) f16 Pt[4 * 32 * LDK]; // per-wave [q 0..31][key]

  int tid  = threadIdx.x;
  int lane = tid & 63, wave = tid >> 6;
  int n    = lane & 15, quad = lane >> 4;
  int quad4 = quad * 4;
  int bh   = blockIdx.y;

  const f16* qg = qb + (size_t)bh * T_SEQ * DHEAD;
  const f16* kg = kb + (size_t)bh * T_SEQ * DHEAD;
  const f16* vg = vb + (size_t)bh * T_SEQ * DHEAD;
  f16* Ptw = Pt + wave * 32 * LDK;
  size_t orow = (size_t)(bh >> 4) * T_SEQ;
  int hcol = (bh & 15) * DHEAD;

  #pragma unroll
  for (int pass = 0; pass < 2; ++pass) {
    int qi = pass == 0 ? (15 - (int)blockIdx.x) : (int)blockIdx.x;  // heavy first
    int qw = qi * 128 + wave * 32;               // this wave's first q row

    // Q fragments (B-operand): lane n holds Q[q=qw+ni*16+n][d=quad*8+j]
    f16x8 qfrag[2][2];
    #pragma unroll
    for (int ni = 0; ni < 2; ++ni)
      #pragma unroll
      for (int kj = 0; kj < 2; ++kj)
        qfrag[ni][kj] = *(const f16x8*)(qg + (size_t)(qw + ni*16 + n)*DHEAD + kj*32 + quad*8);

    f32x4 o[2][4];
    #pragma unroll
    for (int mb = 0; mb < 2; ++mb)
      #pragma unroll
      for (int di = 0; di < 4; ++di) o[mb][di] = f32x4{0.f,0.f,0.f,0.f};
    float lsum[2] = {0.f, 0.f};

    int ntiles = 2 * qi + 2;
    for (int kt = 0; kt < ntiles; ++kt) {
      int kt0 = kt * KT;
      __syncthreads();                           // prev tile fully consumed
      // stage K [64 keys][64 d], coalesced 16B
      #pragma unroll
      for (int it = 0; it < 2; ++it) {
        int idx = tid + it * 256;
        int key = idx >> 3, dq = idx & 7;
        *(uint4*)(Kl + key * LDK + dq * 8) =
            *(const uint4*)(kg + (size_t)(kt0 + key) * DHEAD + dq * 8);
      }
      // stage V transposed, packed f16x2 writes (adjacent keys share a dword)
      {
        int kp = tid & 31, dblk = tid >> 5;      // keys 2kp,2kp+1; d = dblk*8+e
        const f16* v0 = vg + (size_t)(kt0 + 2*kp) * DHEAD + dblk * 8;
        H8 va = *(const H8*)v0;
        H8 vbv = *(const H8*)(v0 + DHEAD);
        #pragma unroll
        for (int e = 0; e < 8; ++e) {
          f16x2 pk2; pk2[0] = va.h[e]; pk2[1] = vbv.h[e];
          *(f16x2*)(Vt + (dblk*8 + e) * LDK + 2*kp) = pk2;
        }
      }
      __syncthreads();

      if (kt0 > qw + 31) continue;               // fully masked for this wave
      bool need_mask = (kt0 + KT - 1) > qw;      // diagonal tile

      // S^T = K Q^T : [64 key][32 q]; lane holds (key=mi*16+quad4+r, q=ni*16+n)
      f32x4 st[4][2];
      #pragma unroll
      for (int mi = 0; mi < 4; ++mi)
        #pragma unroll
        for (int ni = 0; ni < 2; ++ni) st[mi][ni] = f32x4{0.f,0.f,0.f,0.f};
      #pragma unroll
      for (int kj = 0; kj < 2; ++kj) {
        #pragma unroll
        for (int mi = 0; mi < 4; ++mi) {
          f16x8 kf = *(const f16x8*)(Kl + (mi*16 + n) * LDK + kj*32 + quad*8);
          #pragma unroll
          for (int ni = 0; ni < 2; ++ni)
            st[mi][ni] = __builtin_amdgcn_mfma_f32_16x16x32_f16(kf, qfrag[ni][kj], st[mi][ni], 0, 0, 0);
        }
      }

      // p = exp2(s'); per-lane row-sum accumulate; P^T -> LDS (b64, key-contig)
      #pragma unroll
      for (int ni = 0; ni < 2; ++ni) {
        #pragma unroll
        for (int mi = 0; mi < 4; ++mi) {
          f16x4 pk;
          #pragma unroll
          for (int r = 0; r < 4; ++r) {
            float sv = st[mi][ni][r];
            if (need_mask) {
              int key = kt0 + mi*16 + quad4 + r;
              int qq  = qw  + ni*16 + n;
              if (key > qq) sv = -1e30f;
            }
            float p = __builtin_amdgcn_exp2f(sv);
            lsum[ni] += p;
            pk[r] = (f16)p;
          }
          *(f16x4*)(Ptw + (ni*16 + n) * LDK + mi*16 + quad4) = pk;
        }
      }

      // O += P V : A-frag = Pt rows (b128, same-wave RAW), B-frag = Vt rows
      #pragma unroll
      for (int kj = 0; kj < 2; ++kj) {
        f16x8 pf[2];
        #pragma unroll
        for (int mb = 0; mb < 2; ++mb)
          pf[mb] = *(const f16x8*)(Ptw + (mb*16 + n) * LDK + kj*32 + quad*8);
        #pragma unroll
        for (int di = 0; di < 4; ++di) {
          f16x8 vf = *(const f16x8*)(Vt + (di*16 + n) * LDK + kj*32 + quad*8);
          #pragma unroll
          for (int mb = 0; mb < 2; ++mb)
            o[mb][di] = __builtin_amdgcn_mfma_f32_16x16x32_f16(pf[mb], vf, o[mb][di], 0, 0, 0);
        }
      }
    }

    // finish l: quads hold disjoint key-subsets of each q-row -> 2 shuffles
    #pragma unroll
    for (int ni = 0; ni < 2; ++ni) {
      lsum[ni] += __shfl_xor(lsum[ni], 16, 64);
      lsum[ni] += __shfl_xor(lsum[ni], 32, 64);
    }
    // epilogue: O C-layout lane holds (q=mb*16+quad4+r, d=di*16+n)
    #pragma unroll
    for (int mb = 0; mb < 2; ++mb) {
      #pragma unroll
      for (int r = 0; r < 4; ++r) {
        float lv  = __shfl(lsum[mb], quad4 + r, 64);   // lane n'=quad4+r holds q's sum
        float inv = 1.f / lv;
        int t = qw + mb*16 + quad4 + r;
        #pragma unroll
        for (int di = 0; di < 4; ++di)
          attnb[(orow + t) * D_MODEL + hcol + di*16 + n] = (f16)(o[mb][di][r] * inv);
      }
    }
  }
}

extern "C" void kernel_launch(void* const* d_in, const int* in_sizes, int n_in,
                              void* d_out, int out_size, void* d_ws, size_t ws_size,
                              hipStream_t stream)
{
  const float* x     = (const float*)d_in[0];
  const float* Wq    = (const float*)d_in[1];
  const float* Wk    = (const float*)d_in[2];
  const float* Wv    = (const float*)d_in[3];
  const float* Wproj = (const float*)d_in[4];
  const float* bproj = (const float*)d_in[5];
  const float* W1    = (const float*)d_in[6];
  const float* b1    = (const float*)d_in[7];
  const float* W2    = (const float*)d_in[8];
  const float* b2    = (const float*)d_in[9];
  const float* g1    = (const float*)d_in[10];
  const float* bt1   = (const float*)d_in[11];
  const float* g2    = (const float*)d_in[12];
  const float* bt2   = (const float*)d_in[13];
  float* out = (float*)d_out;
  (void)in_sizes; (void)n_in; (void)out_size; (void)ws_size;

  char* ws = (char*)d_ws;
  const size_t SZ_H16 = (size_t)NTOK * D_MODEL * 2;  // 16.78 MB
  const size_t SZ_F32 = (size_t)NTOK * D_MODEL * 4;  // 33.55 MB
  f16*   qb      = (f16*)(ws + 0);
  f16*   kb      = (f16*)(ws + 1 * SZ_H16);
  f16*   vb      = (f16*)(ws + 2 * SZ_H16);
  f16*   attnb   = (f16*)(ws + 3 * SZ_H16);
  f16*   hbuf    = (f16*)(ws + 0);                   // reuses q/k/v/attn after proj (67.1MB)
  float* x1f     = (float*)(ws + 4 * SZ_H16);        // becomes x2 in-place at proj
  f16*   x1h     = (f16*)(ws + 4 * SZ_H16 + SZ_F32);
  float* x3f     = (float*)(ws + 5 * SZ_H16 + SZ_F32);
  f16*   x3h     = (f16*)(ws + 5 * SZ_H16 + 2 * SZ_F32);
  char*  wb      = ws + 6 * SZ_H16 + 2 * SZ_F32;
  f16*   Wqkv_t  = (f16*)(wb);                                       // [3072][1024]
  f16*   Wproj_t = (f16*)(wb + (size_t)3072*1024*2);                 // [1024][1024]
  f16*   W1_t    = (f16*)(wb + (size_t)(3072+1024)*1024*2);          // [4096][1024]
  f16*   W2_t    = (f16*)(wb + (size_t)(3072+1024+4096)*1024*2);     // [1024][4096]

  dim3 blk(256);
  // ---- pack weights to f16 B^T layouts
  transpose_pack<<<dim3(32, 2, 16), blk, 0, stream>>>(Wq, Wqkv_t,                 1024, 64,  65536, 65536);
  transpose_pack<<<dim3(32, 2, 16), blk, 0, stream>>>(Wk, Wqkv_t + 1024*1024,     1024, 64,  65536, 65536);
  transpose_pack<<<dim3(32, 2, 16), blk, 0, stream>>>(Wv, Wqkv_t + 2*1024*1024,   1024, 64,  65536, 65536);
  transpose_pack<<<dim3(32, 32, 1), blk, 0, stream>>>(Wproj, Wproj_t, 1024, 1024, 0, 0);
  transpose_pack<<<dim3(32, 128, 1), blk, 0, stream>>>(W1, W1_t, 1024, 4096, 0, 0);
  transpose_pack<<<dim3(128, 32, 1), blk, 0, stream>>>(W2, W2_t, 4096, 1024, 0, 0);
  // ---- ln1
  ln_kernel<<<NTOK, blk, 0, stream>>>(x, g1, bt1, x1f, x1h);
  // ---- fused QKV gemm [8192,1024] x [1024,3072]
  gemm_kernel<0><<<dim3(64, 24), blk, 0, stream>>>(x1h, Wqkv_t, 1024, nullptr, nullptr, nullptr, qb, kb, vb);
  // ---- attention (MFMA flash, S^T + fixed-max)
  attn_mfma<<<dim3(8, 64), blk, 0, stream>>>(qb, kb, vb, attnb);
  // ---- proj + bias + residual(x1) -> x2 (in place over x1f)
  gemm_kernel<1><<<dim3(64, 8), blk, 0, stream>>>(attnb, Wproj_t, 1024, bproj, x1f, x1f, nullptr, nullptr, nullptr);
  // ---- ln2
  ln_kernel<<<NTOK, blk, 0, stream>>>(x1f, g2, bt2, x3f, x3h);
  // ---- ffn1: relu(x3 @ W1 + b1)
  gemm_kernel<2><<<dim3(64, 32), blk, 0, stream>>>(x3h, W1_t, 1024, b1, nullptr, nullptr, hbuf, nullptr, nullptr);
  // ---- ffn2: x3 + h @ W2 + b2 -> out
  gemm_kernel<3><<<dim3(64, 8), blk, 0, stream>>>(hbuf, W2_t, 4096, b2, x3f, out, nullptr, nullptr, nullptr);
}

// Round 7
// 520.527 us; speedup vs baseline: 1.2826x; 1.0309x over previous
//
#include <hip/hip_runtime.h>
#include <cstdint>

typedef _Float16 f16;
typedef __attribute__((ext_vector_type(8))) _Float16 f16x8;
typedef __attribute__((ext_vector_type(4))) _Float16 f16x4;
typedef __attribute__((ext_vector_type(2))) _Float16 f16x2;
typedef __attribute__((ext_vector_type(4))) float f32x4;
typedef __attribute__((ext_vector_type(16))) float f32x16;

#define D_MODEL 1024
#define T_SEQ   2048
#define NTOK    8192      // B*T
#define DFF     4096
#define DHEAD   64

struct alignas(16) H8 { f16 h[8]; };

// async global->LDS, 16B per lane. LDS dest must be wave-uniform base; HW adds lane*16.
__device__ __forceinline__ void load_lds16(const void* gp, void* lp) {
  __builtin_amdgcn_global_load_lds(
      (const __attribute__((address_space(1))) unsigned int*)(unsigned long long)(uintptr_t)gp,
      (__attribute__((address_space(3))) unsigned int*)(unsigned int)(uintptr_t)lp,
      16, 0, 0);
}

// out[c][r] = (f16) in[r][c];  in: [rows][cols] fp32 row-major. All dims %32==0.
__global__ __launch_bounds__(256) void transpose_pack(
    const float* __restrict__ in, f16* __restrict__ out,
    int rows, int cols, long long in_slice, long long out_slice)
{
  __shared__ float tile[32][33];
  const float* inp = in + (size_t)blockIdx.z * in_slice;
  f16* outp = out + (size_t)blockIdx.z * out_slice;
  int r0 = blockIdx.x * 32, c0 = blockIdx.y * 32;
  int tx = threadIdx.x & 31, ty = threadIdx.x >> 5;   // 32 x 8
  #pragma unroll
  for (int i = 0; i < 4; ++i)
    tile[ty + i*8][tx] = inp[(size_t)(r0 + ty + i*8)*cols + c0 + tx];
  __syncthreads();
  #pragma unroll
  for (int i = 0; i < 4; ++i)
    outp[(size_t)(c0 + ty + i*8)*rows + r0 + tx] = (f16)tile[tx][ty + i*8];
}

// row-wise layernorm over 1024; writes fp32 (residual path) + f16 (GEMM input)
__global__ __launch_bounds__(256) void ln_kernel(
    const float* __restrict__ x, const float* __restrict__ g, const float* __restrict__ b,
    float* __restrict__ outf, f16* __restrict__ outh)
{
  int row = blockIdx.x;
  const float* xr = x + (size_t)row * D_MODEL;
  int tid = threadIdx.x;
  float v[4];
  float s = 0.f;
  #pragma unroll
  for (int i = 0; i < 4; ++i) { v[i] = xr[tid + i*256]; s += v[i]; }
  #pragma unroll
  for (int off = 32; off > 0; off >>= 1) s += __shfl_down(s, off, 64);
  __shared__ float red1[4], red2[4];
  if ((tid & 63) == 0) red1[tid >> 6] = s;
  __syncthreads();
  float mean = (red1[0] + red1[1] + red1[2] + red1[3]) * (1.f / D_MODEL);
  float s2 = 0.f;
  #pragma unroll
  for (int i = 0; i < 4; ++i) { float d = v[i] - mean; s2 += d * d; }
  #pragma unroll
  for (int off = 32; off > 0; off >>= 1) s2 += __shfl_down(s2, off, 64);
  if ((tid & 63) == 0) red2[tid >> 6] = s2;
  __syncthreads();
  float var = (red2[0] + red2[1] + red2[2] + red2[3]) * (1.f / D_MODEL);
  float rstd = rsqrtf(var + 1e-5f);
  #pragma unroll
  for (int i = 0; i < 4; ++i) {
    int c = tid + i*256;
    float y = (v[i] - mean) * rstd * g[c] + b[c];
    outf[(size_t)row*D_MODEL + c] = y;
    outh[(size_t)row*D_MODEL + c] = (f16)y;
  }
}

// GEMM: C[M,N] = A[M,K] * BT[N,K]^T, f16 in, fp32 acc, 32x32x16 MFMA.
// 128x128 block, BK=64 (16 MFMA between barrier pairs -- amortize the
// vmcnt(0)+s_barrier drain, which R6 counters showed to be ~58% of cycles).
// Bank swizzle for BK=64 (row stride = 128B = full bank wrap, so rows give no
// bank spread): LDS slot (row,pos) holds global k-chunk (pos ^ (row&7));
// frag reads use chunk = logical ^ (rl&7) -> 8 lanes/cycle cover 32 banks.
// MODE 0: scatter q/k/v (q scaled log2e/32) -> o0,o1,o2 [BH][T][64] f16
// MODE 1: outf = acc + bias[col] + resid[idx]            (proj, fp32)
// MODE 2: o0   = relu(acc + bias[col])                   (ffn1, f16, ld 4096)
// MODE 3: outf = acc + bias[col] + resid[idx]            (ffn2 -> d_out)
template<int MODE>
__global__ __launch_bounds__(256) void gemm_kernel(
    const f16* __restrict__ A, const f16* __restrict__ BT, int K,
    const float* __restrict__ bias, const float* __restrict__ resid,
    float* __restrict__ outf, f16* __restrict__ o0, f16* __restrict__ o1, f16* __restrict__ o2)
{
  constexpr int BM = 128, BN = 128, BK = 64;
  __shared__ __align__(16) f16 As[BM * BK];   // 16 KB
  __shared__ __align__(16) f16 Bs[BN * BK];   // 16 KB
  int tid  = threadIdx.x;
  int lane = tid & 63;
  int wave = tid >> 6;
  int wm = (wave >> 1) * 64, wn = (wave & 1) * 64;
  size_t row0 = (size_t)blockIdx.x * BM, col0 = (size_t)blockIdx.y * BN;
  int rl = lane & 31;             // row/col within 32-tile
  int half = lane >> 5;           // k-half of the wave
  int swz = rl & 7;               // read-side chunk swizzle for this lane's rows

  f32x16 acc[2][2];
  #pragma unroll
  for (int i = 0; i < 2; ++i)
    #pragma unroll
    for (int j = 0; j < 2; ++j)
      acc[i][j] = (f32x16)(0.f);

  const f16* a_base = A  + row0 * K;
  const f16* b_base = BT + col0 * K;

  for (int k0 = 0; k0 < K; k0 += BK) {
    __syncthreads();
    // stage A+B: 1024 chunks each; slot (row=c>>3, pos=c&7) holds global
    // k-chunk (pos ^ (row&7))  [swizzle is in the SOURCE address only]
    #pragma unroll
    for (int i = 0; i < 4; ++i) {
      int c  = tid + i * 256;
      int rr = c >> 3;
      int cg = (c & 7) ^ (rr & 7);
      load_lds16(a_base + (size_t)rr * K + k0 + cg * 8, As + (size_t)(c & ~63) * 8);
      load_lds16(b_base + (size_t)rr * K + k0 + cg * 8, Bs + (size_t)(c & ~63) * 8);
    }
    __syncthreads();   // drains vmcnt for global_load_lds
    // frags (32x32x16): lane holds [m=rl][k = half*8 + j]; logical chunk ks*2+half
    #pragma unroll
    for (int ks = 0; ks < 4; ++ks) {
      int chunk = (ks * 2 + half) ^ swz;
      f16x8 fa[2], fb[2];
      #pragma unroll
      for (int mi = 0; mi < 2; ++mi)
        fa[mi] = *(const f16x8*)(As + (wm + mi*32 + rl) * BK + chunk * 8);
      #pragma unroll
      for (int ni = 0; ni < 2; ++ni)
        fb[ni] = *(const f16x8*)(Bs + (wn + ni*32 + rl) * BK + chunk * 8);
      #pragma unroll
      for (int mi = 0; mi < 2; ++mi)
        #pragma unroll
        for (int ni = 0; ni < 2; ++ni)
          acc[mi][ni] = __builtin_amdgcn_mfma_f32_32x32x16_f16(fa[mi], fb[ni], acc[mi][ni], 0, 0, 0);
    }
  }

  // epilogue: 32x32 C layout (m74/m101): col=lane&31, row=(reg&3)+8*(reg>>2)+4*(lane>>5)
  int rbase = half * 4;
  #pragma unroll
  for (int mi = 0; mi < 2; ++mi) {
    #pragma unroll
    for (int ni = 0; ni < 2; ++ni) {
      #pragma unroll
      for (int r = 0; r < 16; ++r) {
        size_t grow = row0 + wm + mi*32 + rbase + (r & 3) + 8 * (r >> 2);
        size_t gcol = col0 + wn + ni*32 + rl;
        float v = acc[mi][ni][r];
        if constexpr (MODE == 0) {
          int sel = (int)(gcol >> 10);
          int hh  = ((int)gcol >> 6) & 15;
          int dd  = (int)gcol & 63;
          f16* dst = (sel == 0) ? o0 : ((sel == 1) ? o1 : o2);
          if (sel == 0) v *= 0.045084229f;   // (1/32) * log2(e): exp2-domain scores
          size_t bh = (grow >> 11) * 16 + hh;
          dst[(bh * T_SEQ + (grow & 2047)) * DHEAD + dd] = (f16)v;
        } else if constexpr (MODE == 1 || MODE == 3) {
          size_t idx = grow * D_MODEL + gcol;
          outf[idx] = v + bias[gcol] + resid[idx];
        } else {  // MODE 2
          float t = v + bias[gcol];
          o0[grow * (size_t)DFF + gcol] = (f16)(t > 0.f ? t : 0.f);
        }
      }
    }
  }
}

// MFMA flash attention, S^T formulation + fixed-max softmax.
// Block = 4 waves x 32 q-rows = 128 q-rows; two q-tiles per block (qi=15-bx, bx)
// for uniform 34 k-tiles/block. Scores arrive already in log2 domain (q scaled
// by log2e/32 at QKV epilogue), softmax max fixed at 0 (scores have std ~0.36
// in log2 domain -- exp2 cannot overflow; softmax is shift-invariant so exact).
// S^T = K*Q^T puts each q-row's keys in ONE lane's registers: no per-tile
// shuffles; P^T lane data is key-contiguous -> b64 LDS writes, b128 A-frag reads.
__global__ __launch_bounds__(256) void attn_mfma(
    const f16* __restrict__ qb, const f16* __restrict__ kb,
    const f16* __restrict__ vb, f16* __restrict__ attnb)
{
  constexpr int KT  = 64;
  constexpr int LDK = 72;                        // padded f16 stride (K, Vt, Pt)
  __shared__ __align__(16) f16 Kl[KT * LDK];     // [key][d]
  __shared__ __align__(16) f16 Vt[DHEAD * LDK];  // [d][key]
  __shared__ __align__(16) f16 Pt[4 * 32 * LDK]; // per-wave [q 0..31][key]

  int tid  = threadIdx.x;
  int lane = tid & 63, wave = tid >> 6;
  int n    = lane & 15, quad = lane >> 4;
  int quad4 = quad * 4;
  int bh   = blockIdx.y;

  const f16* qg = qb + (size_t)bh * T_SEQ * DHEAD;
  const f16* kg = kb + (size_t)bh * T_SEQ * DHEAD;
  const f16* vg = vb + (size_t)bh * T_SEQ * DHEAD;
  f16* Ptw = Pt + wave * 32 * LDK;
  size_t orow = (size_t)(bh >> 4) * T_SEQ;
  int hcol = (bh & 15) * DHEAD;

  #pragma unroll
  for (int pass = 0; pass < 2; ++pass) {
    int qi = pass == 0 ? (15 - (int)blockIdx.x) : (int)blockIdx.x;  // heavy first
    int qw = qi * 128 + wave * 32;               // this wave's first q row

    // Q fragments (B-operand): lane n holds Q[q=qw+ni*16+n][d=quad*8+j]
    f16x8 qfrag[2][2];
    #pragma unroll
    for (int ni = 0; ni < 2; ++ni)
      #pragma unroll
      for (int kj = 0; kj < 2; ++kj)
        qfrag[ni][kj] = *(const f16x8*)(qg + (size_t)(qw + ni*16 + n)*DHEAD + kj*32 + quad*8);

    f32x4 o[2][4];
    #pragma unroll
    for (int mb = 0; mb < 2; ++mb)
      #pragma unroll
      for (int di = 0; di < 4; ++di) o[mb][di] = f32x4{0.f,0.f,0.f,0.f};
    float lsum[2] = {0.f, 0.f};

    int ntiles = 2 * qi + 2;
    for (int kt = 0; kt < ntiles; ++kt) {
      int kt0 = kt * KT;
      __syncthreads();                           // prev tile fully consumed
      // stage K [64 keys][64 d], coalesced 16B
      #pragma unroll
      for (int it = 0; it < 2; ++it) {
        int idx = tid + it * 256;
        int key = idx >> 3, dq = idx & 7;
        *(uint4*)(Kl + key * LDK + dq * 8) =
            *(const uint4*)(kg + (size_t)(kt0 + key) * DHEAD + dq * 8);
      }
      // stage V transposed, packed f16x2 writes (adjacent keys share a dword)
      {
        int kp = tid & 31, dblk = tid >> 5;      // keys 2kp,2kp+1; d = dblk*8+e
        const f16* v0 = vg + (size_t)(kt0 + 2*kp) * DHEAD + dblk * 8;
        H8 va = *(const H8*)v0;
        H8 vbv = *(const H8*)(v0 + DHEAD);
        #pragma unroll
        for (int e = 0; e < 8; ++e) {
          f16x2 pk2; pk2[0] = va.h[e]; pk2[1] = vbv.h[e];
          *(f16x2*)(Vt + (dblk*8 + e) * LDK + 2*kp) = pk2;
        }
      }
      __syncthreads();

      if (kt0 > qw + 31) continue;               // fully masked for this wave
      bool need_mask = (kt0 + KT - 1) > qw;      // diagonal tile

      // S^T = K Q^T : [64 key][32 q]; lane holds (key=mi*16+quad4+r, q=ni*16+n)
      f32x4 st[4][2];
      #pragma unroll
      for (int mi = 0; mi < 4; ++mi)
        #pragma unroll
        for (int ni = 0; ni < 2; ++ni) st[mi][ni] = f32x4{0.f,0.f,0.f,0.f};
      #pragma unroll
      for (int kj = 0; kj < 2; ++kj) {
        #pragma unroll
        for (int mi = 0; mi < 4; ++mi) {
          f16x8 kf = *(const f16x8*)(Kl + (mi*16 + n) * LDK + kj*32 + quad*8);
          #pragma unroll
          for (int ni = 0; ni < 2; ++ni)
            st[mi][ni] = __builtin_amdgcn_mfma_f32_16x16x32_f16(kf, qfrag[ni][kj], st[mi][ni], 0, 0, 0);
        }
      }

      // p = exp2(s'); per-lane row-sum accumulate; P^T -> LDS (b64, key-contig)
      #pragma unroll
      for (int ni = 0; ni < 2; ++ni) {
        #pragma unroll
        for (int mi = 0; mi < 4; ++mi) {
          f16x4 pk;
          #pragma unroll
          for (int r = 0; r < 4; ++r) {
            float sv = st[mi][ni][r];
            if (need_mask) {
              int key = kt0 + mi*16 + quad4 + r;
              int qq  = qw  + ni*16 + n;
              if (key > qq) sv = -1e30f;
            }
            float p = __builtin_amdgcn_exp2f(sv);
            lsum[ni] += p;
            pk[r] = (f16)p;
          }
          *(f16x4*)(Ptw + (ni*16 + n) * LDK + mi*16 + quad4) = pk;
        }
      }

      // O += P V : A-frag = Pt rows (b128, same-wave RAW), B-frag = Vt rows
      #pragma unroll
      for (int kj = 0; kj < 2; ++kj) {
        f16x8 pf[2];
        #pragma unroll
        for (int mb = 0; mb < 2; ++mb)
          pf[mb] = *(const f16x8*)(Ptw + (mb*16 + n) * LDK + kj*32 + quad*8);
        #pragma unroll
        for (int di = 0; di < 4; ++di) {
          f16x8 vf = *(const f16x8*)(Vt + (di*16 + n) * LDK + kj*32 + quad*8);
          #pragma unroll
          for (int mb = 0; mb < 2; ++mb)
            o[mb][di] = __builtin_amdgcn_mfma_f32_16x16x32_f16(pf[mb], vf, o[mb][di], 0, 0, 0);
        }
      }
    }

    // finish l: quads hold disjoint key-subsets of each q-row -> 2 shuffles
    #pragma unroll
    for (int ni = 0; ni < 2; ++ni) {
      lsum[ni] += __shfl_xor(lsum[ni], 16, 64);
      lsum[ni] += __shfl_xor(lsum[ni], 32, 64);
    }
    // epilogue: O C-layout lane holds (q=mb*16+quad4+r, d=di*16+n)
    #pragma unroll
    for (int mb = 0; mb < 2; ++mb) {
      #pragma unroll
      for (int r = 0; r < 4; ++r) {
        float lv  = __shfl(lsum[mb], quad4 + r, 64);   // lane n'=quad4+r holds q's sum
        float inv = 1.f / lv;
        int t = qw + mb*16 + quad4 + r;
        #pragma unroll
        for (int di = 0; di < 4; ++di)
          attnb[(orow + t) * D_MODEL + hcol + di*16 + n] = (f16)(o[mb][di][r] * inv);
      }
    }
  }
}

extern "C" void kernel_launch(void* const* d_in, const int* in_sizes, int n_in,
                              void* d_out, int out_size, void* d_ws, size_t ws_size,
                              hipStream_t stream)
{
  const float* x     = (const float*)d_in[0];
  const float* Wq    = (const float*)d_in[1];
  const float* Wk    = (const float*)d_in[2];
  const float* Wv    = (const float*)d_in[3];
  const float* Wproj = (const float*)d_in[4];
  const float* bproj = (const float*)d_in[5];
  const float* W1    = (const float*)d_in[6];
  const float* b1    = (const float*)d_in[7];
  const float* W2    = (const float*)d_in[8];
  const float* b2    = (const float*)d_in[9];
  const float* g1    = (const float*)d_in[10];
  const float* bt1   = (const float*)d_in[11];
  const float* g2    = (const float*)d_in[12];
  const float* bt2   = (const float*)d_in[13];
  float* out = (float*)d_out;
  (void)in_sizes; (void)n_in; (void)out_size; (void)ws_size;

  char* ws = (char*)d_ws;
  const size_t SZ_H16 = (size_t)NTOK * D_MODEL * 2;  // 16.78 MB
  const size_t SZ_F32 = (size_t)NTOK * D_MODEL * 4;  // 33.55 MB
  f16*   qb      = (f16*)(ws + 0);
  f16*   kb      = (f16*)(ws + 1 * SZ_H16);
  f16*   vb      = (f16*)(ws + 2 * SZ_H16);
  f16*   attnb   = (f16*)(ws + 3 * SZ_H16);
  f16*   hbuf    = (f16*)(ws + 0);                   // reuses q/k/v/attn after proj (67.1MB)
  float* x1f     = (float*)(ws + 4 * SZ_H16);        // becomes x2 in-place at proj
  f16*   x1h     = (f16*)(ws + 4 * SZ_H16 + SZ_F32);
  float* x3f     = (float*)(ws + 5 * SZ_H16 + SZ_F32);
  f16*   x3h     = (f16*)(ws + 5 * SZ_H16 + 2 * SZ_F32);
  char*  wb      = ws + 6 * SZ_H16 + 2 * SZ_F32;
  f16*   Wqkv_t  = (f16*)(wb);                                       // [3072][1024]
  f16*   Wproj_t = (f16*)(wb + (size_t)3072*1024*2);                 // [1024][1024]
  f16*   W1_t    = (f16*)(wb + (size_t)(3072+1024)*1024*2);          // [4096][1024]
  f16*   W2_t    = (f16*)(wb + (size_t)(3072+1024+4096)*1024*2);     // [1024][4096]

  dim3 blk(256);
  // ---- pack weights to f16 B^T layouts
  transpose_pack<<<dim3(32, 2, 16), blk, 0, stream>>>(Wq, Wqkv_t,                 1024, 64,  65536, 65536);
  transpose_pack<<<dim3(32, 2, 16), blk, 0, stream>>>(Wk, Wqkv_t + 1024*1024,     1024, 64,  65536, 65536);
  transpose_pack<<<dim3(32, 2, 16), blk, 0, stream>>>(Wv, Wqkv_t + 2*1024*1024,   1024, 64,  65536, 65536);
  transpose_pack<<<dim3(32, 32, 1), blk, 0, stream>>>(Wproj, Wproj_t, 1024, 1024, 0, 0);
  transpose_pack<<<dim3(32, 128, 1), blk, 0, stream>>>(W1, W1_t, 1024, 4096, 0, 0);
  transpose_pack<<<dim3(128, 32, 1), blk, 0, stream>>>(W2, W2_t, 4096, 1024, 0, 0);
  // ---- ln1
  ln_kernel<<<NTOK, blk, 0, stream>>>(x, g1, bt1, x1f, x1h);
  // ---- fused QKV gemm [8192,1024] x [1024,3072]
  gemm_kernel<0><<<dim3(64, 24), blk, 0, stream>>>(x1h, Wqkv_t, 1024, nullptr, nullptr, nullptr, qb, kb, vb);
  // ---- attention (MFMA flash, S^T + fixed-max)
  attn_mfma<<<dim3(8, 64), blk, 0, stream>>>(qb, kb, vb, attnb);
  // ---- proj + bias + residual(x1) -> x2 (in place over x1f)
  gemm_kernel<1><<<dim3(64, 8), blk, 0, stream>>>(attnb, Wproj_t, 1024, bproj, x1f, x1f, nullptr, nullptr, nullptr);
  // ---- ln2
  ln_kernel<<<NTOK, blk, 0, stream>>>(x1f, g2, bt2, x3f, x3h);
  // ---- ffn1: relu(x3 @ W1 + b1)
  gemm_kernel<2><<<dim3(64, 32), blk, 0, stream>>>(x3h, W1_t, 1024, b1, nullptr, nullptr, hbuf, nullptr, nullptr);
  // ---- ffn2: x3 + h @ W2 + b2 -> out
  gemm_kernel<3><<<dim3(64, 8), blk, 0, stream>>>(hbuf, W2_t, 4096, b2, x3f, out, nullptr, nullptr, nullptr);
}